// Round 1
// baseline (362.270 us; speedup 1.0000x reference)
//
#include <hip/hip_runtime.h>
#include <hip/hip_bf16.h>
#include <math.h>

// Problem constants (B=8, S=4096, F=768, N=128)
constexpr int kF = 768;
constexpr int kN = 128;
constexpr int kB = 8;
constexpr int kS = 4096;
constexpr int kM = kB * kS;          // 32768 rows
constexpr int kChunks = 128;         // scan chunks along S
constexpr int kClen = 32;            // kChunks * kClen == kS

// Workspace layout (float offsets)
// [0,256)        A_bar   (re at n, im at 128+n)
// [256,512)      A_bar^kClen
// [512,768)      coef = (A_bar-1)/(A_diag+1e-8)
// [768, +196608) Bbar_t  [768][256]  (col n = re, col 128+n = im)
// [197376, +196608) Ct   [256][768]  (row n = C_re[:,n], row 128+n = -C_im[:,n])
// [393984, +262144) finals  [8*128][256]
// [656128, +262144) carries [8*128][256]
// [918272, +8388608) Bu / x  [32768][256]
constexpr size_t kOffBbar    = 768;
constexpr size_t kOffCt      = 197376;
constexpr size_t kOffFinals  = 393984;
constexpr size_t kOffCarries = 656128;
constexpr size_t kOffBu      = 918272;

__global__ __launch_bounds__(128)
void pre1(const float* __restrict__ log_A_real, const float* __restrict__ A_imag,
          const float* __restrict__ log_dt, float* __restrict__ ws) {
    int n = threadIdx.x;
    float dt = expf(log_dt[n]);
    float ar = -expf(log_A_real[n]);
    float ai = A_imag[n];
    float er = expf(ar * dt);
    float Ar = er * cosf(ai * dt);
    float Ai = er * sinf(ai * dt);
    // coef = (A_bar - 1) / (A_diag + 1e-8)
    float dr = ar + 1e-8f, di = ai;
    float inv = 1.0f / (dr * dr + di * di);
    float nr = Ar - 1.0f, ni = Ai;
    float cr = (nr * dr + ni * di) * inv;
    float ci = (ni * dr - nr * di) * inv;
    // A_bar^kClen by repeated multiply (matches scan semantics)
    float pr = 1.f, pi = 0.f;
    for (int i = 0; i < kClen; ++i) {
        float t = pr * Ar - pi * Ai;
        pi = pr * Ai + pi * Ar;
        pr = t;
    }
    ws[n] = Ar;        ws[128 + n] = Ai;
    ws[256 + n] = pr;  ws[384 + n] = pi;
    ws[512 + n] = cr;  ws[640 + n] = ci;
}

// Bbar_t[f][col] : col<128 -> Re(coef_n * B_n_f), col>=128 -> Im(...)
__global__ __launch_bounds__(256)
void pre2(const float* __restrict__ B_re, const float* __restrict__ B_im,
          float* __restrict__ ws) {
    int id = blockIdx.x * 256 + threadIdx.x;   // 0 .. 768*256-1
    int f = id >> 8;
    int col = id & 255;
    int n = col & 127;
    float cr = ws[512 + n], ci = ws[640 + n];
    float br = B_re[n * kF + f], bi = B_im[n * kF + f];
    float v = (col < 128) ? (cr * br - ci * bi) : (cr * bi + ci * br);
    ws[kOffBbar + id] = v;
}

// Ct[row][f] : row<128 -> C_re[f][row], row>=128 -> -C_im[f][row-128]
__global__ __launch_bounds__(256)
void pre3(const float* __restrict__ C_re, const float* __restrict__ C_im,
          float* __restrict__ ws) {
    int id = blockIdx.x * 256 + threadIdx.x;   // 0 .. 256*768-1
    int row = id / kF;
    int f = id - row * kF;
    int n = row & 127;
    float v = (row < 128) ? C_re[f * kN + n] : -C_im[f * kN + n];
    ws[kOffCt + id] = v;
}

// 128x128 tile fp32 GEMM: C[M][Nc] = A[M][K] * Bt[K][Nc]; optional epilogue += D[col]*U[row][col]
template<bool EPI>
__global__ __launch_bounds__(256)
void gemm128(const float* __restrict__ A, const float* __restrict__ Bt,
             float* __restrict__ Cout, int M, int Nc, int K,
             const float* __restrict__ Dp, const float* __restrict__ Up) {
    __shared__ float As[16][136];
    __shared__ float Bs[16][136];
    const int m0 = blockIdx.y * 128;
    const int n0 = blockIdx.x * 128;
    const int t = threadIdx.x;
    const int tx = t & 15, ty = t >> 4;

    float acc[8][8];
#pragma unroll
    for (int i = 0; i < 8; ++i)
#pragma unroll
        for (int j = 0; j < 8; ++j) acc[i][j] = 0.f;

    for (int k0 = 0; k0 < K; k0 += 16) {
#pragma unroll
        for (int i = 0; i < 2; ++i) {
            int e = t + i * 256;          // 0..511
            int r = e >> 2;               // 0..127
            int kq = (e & 3) << 2;        // 0,4,8,12
            const float4 v = *(const float4*)(A + (size_t)(m0 + r) * K + k0 + kq);
            As[kq + 0][r] = v.x; As[kq + 1][r] = v.y;
            As[kq + 2][r] = v.z; As[kq + 3][r] = v.w;
        }
#pragma unroll
        for (int i = 0; i < 2; ++i) {
            int e = t + i * 256;
            int kk = e >> 5;              // 0..15
            int cq = (e & 31) << 2;       // 0..124
            *(float4*)(&Bs[kk][cq]) = *(const float4*)(Bt + (size_t)(k0 + kk) * Nc + n0 + cq);
        }
        __syncthreads();
#pragma unroll
        for (int kk = 0; kk < 16; ++kk) {
            float a[8], b[8];
            *(float4*)(&a[0]) = *(const float4*)(&As[kk][ty * 8]);
            *(float4*)(&a[4]) = *(const float4*)(&As[kk][ty * 8 + 4]);
            *(float4*)(&b[0]) = *(const float4*)(&Bs[kk][tx * 8]);
            *(float4*)(&b[4]) = *(const float4*)(&Bs[kk][tx * 8 + 4]);
#pragma unroll
            for (int i = 0; i < 8; ++i)
#pragma unroll
                for (int j = 0; j < 8; ++j)
                    acc[i][j] = fmaf(a[i], b[j], acc[i][j]);
        }
        __syncthreads();
    }

#pragma unroll
    for (int i = 0; i < 8; ++i) {
        int row = m0 + ty * 8 + i;
        size_t co = (size_t)row * Nc + n0 + tx * 8;
        if (EPI) {
#pragma unroll
            for (int j = 0; j < 8; ++j) {
                int col = n0 + tx * 8 + j;
                acc[i][j] = fmaf(Dp[col], Up[(size_t)row * Nc + col], acc[i][j]);
            }
        }
        float4 v0 = {acc[i][0], acc[i][1], acc[i][2], acc[i][3]};
        float4 v1 = {acc[i][4], acc[i][5], acc[i][6], acc[i][7]};
        *(float4*)(Cout + co) = v0;
        *(float4*)(Cout + co + 4) = v1;
    }
}

// Phase A: per (b, chunk), local scan with zero init; save chunk-final state.
__global__ __launch_bounds__(128)
void scanA(const float* __restrict__ Bu, const float* __restrict__ wsc,
           float* __restrict__ finals) {
    int n = threadIdx.x;
    int blk = blockIdx.x;            // b*kChunks + c
    int b = blk >> 7, c = blk & 127;
    float Ar = wsc[n], Ai = wsc[128 + n];
    float xr = 0.f, xi = 0.f;
    size_t base = ((size_t)(b * kS + c * kClen)) * 256;
    for (int s = 0; s < kClen; ++s) {
        float br = Bu[base + n], bi = Bu[base + 128 + n];
        float tr = Ar * xr - Ai * xi + br;
        xi = Ar * xi + Ai * xr + bi;
        xr = tr;
        base += 256;
    }
    finals[(size_t)blk * 256 + n] = xr;
    finals[(size_t)blk * 256 + 128 + n] = xi;
}

// Phase B: serial scan over chunk finals -> exclusive carries.
__global__ __launch_bounds__(128)
void scanB(const float* __restrict__ finals, const float* __restrict__ ws,
           float* __restrict__ carries) {
    int n = threadIdx.x;
    int b = blockIdx.x;
    float Pr = ws[256 + n], Pi = ws[384 + n];
    float xr = 0.f, xi = 0.f;
    for (int c = 0; c < kChunks; ++c) {
        size_t o = ((size_t)(b * kChunks + c)) * 256;
        carries[o + n] = xr;
        carries[o + 128 + n] = xi;
        float fr = finals[o + n], fi = finals[o + 128 + n];
        float tr = Pr * xr - Pi * xi + fr;
        xi = Pr * xi + Pi * xr + fi;
        xr = tr;
    }
}

// Phase C: redo local scan seeded with carry; write x over Bu in place.
__global__ __launch_bounds__(128)
void scanC(float* __restrict__ Bu, const float* __restrict__ wsc,
           const float* __restrict__ carries) {
    int n = threadIdx.x;
    int blk = blockIdx.x;
    int b = blk >> 7, c = blk & 127;
    float Ar = wsc[n], Ai = wsc[128 + n];
    size_t co = (size_t)blk * 256;
    float xr = carries[co + n], xi = carries[co + 128 + n];
    size_t base = ((size_t)(b * kS + c * kClen)) * 256;
    for (int s = 0; s < kClen; ++s) {
        float br = Bu[base + n], bi = Bu[base + 128 + n];
        float tr = Ar * xr - Ai * xi + br;
        xi = Ar * xi + Ai * xr + bi;
        xr = tr;
        Bu[base + n] = xr;
        Bu[base + 128 + n] = xi;
        base += 256;
    }
}

extern "C" void kernel_launch(void* const* d_in, const int* in_sizes, int n_in,
                              void* d_out, int out_size, void* d_ws, size_t ws_size,
                              hipStream_t stream) {
    const float* u          = (const float*)d_in[0];
    const float* log_A_real = (const float*)d_in[1];
    const float* A_imag     = (const float*)d_in[2];
    const float* B_re       = (const float*)d_in[3];
    const float* B_im       = (const float*)d_in[4];
    const float* C_re       = (const float*)d_in[5];
    const float* C_im       = (const float*)d_in[6];
    const float* D          = (const float*)d_in[7];
    const float* log_dt     = (const float*)d_in[8];

    float* ws      = (float*)d_ws;
    float* Bbar    = ws + kOffBbar;
    float* Ct      = ws + kOffCt;
    float* finals  = ws + kOffFinals;
    float* carries = ws + kOffCarries;
    float* Bu      = ws + kOffBu;
    float* y       = (float*)d_out;

    pre1<<<1, 128, 0, stream>>>(log_A_real, A_imag, log_dt, ws);
    pre2<<<(kF * 256) / 256, 256, 0, stream>>>(B_re, B_im, ws);
    pre3<<<(256 * kF) / 256, 256, 0, stream>>>(C_re, C_im, ws);

    // Bu[32768][256] = u[32768][768] @ Bbar_t[768][256]
    gemm128<false><<<dim3(2, kM / 128), 256, 0, stream>>>(
        u, Bbar, Bu, kM, 256, kF, nullptr, nullptr);

    scanA<<<kB * kChunks, 128, 0, stream>>>(Bu, ws, finals);
    scanB<<<kB, 128, 0, stream>>>(finals, ws, carries);
    scanC<<<kB * kChunks, 128, 0, stream>>>(Bu, ws, carries);

    // y[32768][768] = x[32768][256] @ Ct[256][768] + D*u
    gemm128<true><<<dim3(kF / 128, kM / 128), 256, 0, stream>>>(
        Bu, Ct, y, kM, kF, 256, D, u);
}

// Round 2
// 146.494 us; speedup vs baseline: 2.4729x; 2.4729x over previous
//
#include <hip/hip_runtime.h>
#include <hip/hip_bf16.h>
#include <math.h>

typedef __attribute__((ext_vector_type(8))) short short8;
typedef __attribute__((ext_vector_type(4))) float f32x4;
typedef __attribute__((ext_vector_type(4))) unsigned int uint4v;

// Problem constants (B=8, S=4096, F=768, N=128)
constexpr int kF = 768;
constexpr int kN = 128;
constexpr int kB = 8;
constexpr int kS = 4096;
constexpr int kM = kB * kS;          // 32768 rows
constexpr int kChunks = 128;         // scan chunks along S
constexpr int kClen = 32;            // kChunks * kClen == kS

// Workspace layout (BYTE offsets); total 37227520 B (same footprint as round 1)
// [0, 3072)            scalars: A_bar(re,im), A_bar^32(re,im), coef(re,im) as floats
// [3072, +393216)      Bw_hi  [256][768] bf16 : row c = output col (c<128 Re, else Im)
// [396288, +393216)    Bw_lo
// [789504, +393216)    Cw_hi  [768][256] bf16 : row f, k<128 = C_re[f][k], else -C_im
// [1182720, +393216)   Cw_lo
// [1575936, +1048576)  finals  [8*128][256] f32
// [2624512, +1048576)  carries [8*128][256] f32
// [3673088, +33554432) Bu / x  [32768][256] f32
constexpr size_t kOffBwHi    = 3072;
constexpr size_t kOffBwLo    = 396288;
constexpr size_t kOffCwHi    = 789504;
constexpr size_t kOffCwLo    = 1182720;
constexpr size_t kOffFinals  = 1575936;
constexpr size_t kOffCarries = 2624512;
constexpr size_t kOffBu      = 3673088;

__device__ __forceinline__ unsigned short f2bf(float f) {
    unsigned int u = __builtin_bit_cast(unsigned int, f);
    u += 0x7fffu + ((u >> 16) & 1u);   // round-to-nearest-even
    return (unsigned short)(u >> 16);
}
__device__ __forceinline__ float bf2f(unsigned short s) {
    unsigned int u = ((unsigned int)s) << 16;
    return __builtin_bit_cast(float, u);
}

__global__ __launch_bounds__(128)
void pre1(const float* __restrict__ log_A_real, const float* __restrict__ A_imag,
          const float* __restrict__ log_dt, float* __restrict__ ws) {
    int n = threadIdx.x;
    float dt = expf(log_dt[n]);
    float ar = -expf(log_A_real[n]);
    float ai = A_imag[n];
    float er = expf(ar * dt);
    float Ar = er * cosf(ai * dt);
    float Ai = er * sinf(ai * dt);
    // coef = (A_bar - 1) / (A_diag + 1e-8)
    float dr = ar + 1e-8f, di = ai;
    float inv = 1.0f / (dr * dr + di * di);
    float nr = Ar - 1.0f, ni = Ai;
    float cr = (nr * dr + ni * di) * inv;
    float ci = (ni * dr - nr * di) * inv;
    // A_bar^kClen by repeated multiply (matches scan semantics)
    float pr = 1.f, pi = 0.f;
    for (int i = 0; i < kClen; ++i) {
        float t = pr * Ar - pi * Ai;
        pi = pr * Ai + pi * Ar;
        pr = t;
    }
    ws[n] = Ar;        ws[128 + n] = Ai;
    ws[256 + n] = pr;  ws[384 + n] = pi;
    ws[512 + n] = cr;  ws[640 + n] = ci;
}

// Bw[c][f], c in [0,256): c<128 -> Re(coef_n * B[n][f]) (n=c), else Im (n=c-128)
__global__ __launch_bounds__(256)
void pre2(const float* __restrict__ B_re, const float* __restrict__ B_im,
          const float* __restrict__ wsf,
          unsigned short* __restrict__ bw_hi, unsigned short* __restrict__ bw_lo) {
    int id = blockIdx.x * 256 + threadIdx.x;   // 0 .. 256*768-1
    int c = id / kF;
    int f = id - c * kF;
    int n = c & 127;
    float cr = wsf[512 + n], ci = wsf[640 + n];
    float br = B_re[n * kF + f], bi = B_im[n * kF + f];
    float v = (c < 128) ? (cr * br - ci * bi) : (cr * bi + ci * br);
    unsigned short h = f2bf(v);
    bw_hi[id] = h;
    bw_lo[id] = f2bf(v - bf2f(h));
}

// Cw[f][k], k in [0,256): k<128 -> C_re[f][k], else -C_im[f][k-128]
__global__ __launch_bounds__(256)
void pre3(const float* __restrict__ C_re, const float* __restrict__ C_im,
          unsigned short* __restrict__ cw_hi, unsigned short* __restrict__ cw_lo) {
    int id = blockIdx.x * 256 + threadIdx.x;   // 0 .. 768*256-1
    int f = id >> 8;
    int k = id & 255;
    float v = (k < 128) ? C_re[f * kN + k] : -C_im[f * kN + (k - 128)];
    unsigned short h = f2bf(v);
    cw_hi[id] = h;
    cw_lo[id] = f2bf(v - bf2f(h));
}

// Split-bf16 MFMA GEMM: Cout[M][Nc] = A[M][K](f32) @ W[Nc][K](bf16 hi/lo, row=out col)
// 128x128 tile, BK=32, 4 waves, each wave 64x64 via 4x4 16x16x32 fragments.
// acc += A_hi*W_hi + A_lo*W_hi + A_hi*W_lo  (drops lo*lo ~ 2^-32)
template<bool EPI>
__global__ __launch_bounds__(256, 2)
void mfma_gemm(const float* __restrict__ A,
               const unsigned short* __restrict__ Wh,
               const unsigned short* __restrict__ Wl,
               float* __restrict__ Cout, int M, int Nc, int K,
               const float* __restrict__ Dp, const float* __restrict__ Up) {
    // stride 40 shorts = 80 B (16B-aligned, 2-way bank alias = free)
    __shared__ short As_hi[128 * 40];
    __shared__ short As_lo[128 * 40];
    __shared__ short Bs_hi[128 * 40];
    __shared__ short Bs_lo[128 * 40];

    // XCD-bijective swizzle (nwg % 8 == 0 for both grids)
    const int gx = gridDim.x;
    const int nwg = gx * gridDim.y;
    const int orig = blockIdx.y * gx + blockIdx.x;
    const int cpx = nwg >> 3;
    const int sw = (orig & 7) * cpx + (orig >> 3);
    const int m0 = (sw / gx) * 128;
    const int n0 = (sw % gx) * 128;

    const int t = threadIdx.x;
    const int sr = t >> 1;        // staging row (A) / col (W): 0..127
    const int sh = t & 1;         // which 16-wide half of the 32-k tile

    const int wave = t >> 6, lane = t & 63;
    const int wr = wave >> 1, wc = wave & 1;  // wave tile (64x64) coords
    const int lr = lane & 15, lg = lane >> 4;

    f32x4 acc[4][4] = {};

    const int KT = K >> 5;

    // staging registers (prefetched one K-tile ahead)
    f32x4 av[4];
    uint4v bvh[2], bvl[2];

    auto load_tile = [&](int kt) {
        const int k0 = kt << 5;
        const float* ap = A + (size_t)(m0 + sr) * K + k0 + sh * 16;
        av[0] = *(const f32x4*)(ap);
        av[1] = *(const f32x4*)(ap + 4);
        av[2] = *(const f32x4*)(ap + 8);
        av[3] = *(const f32x4*)(ap + 12);
        const unsigned short* wh = Wh + (size_t)(n0 + sr) * K + k0 + sh * 16;
        const unsigned short* wl = Wl + (size_t)(n0 + sr) * K + k0 + sh * 16;
        bvh[0] = *(const uint4v*)(wh);
        bvh[1] = *(const uint4v*)(wh + 8);
        bvl[0] = *(const uint4v*)(wl);
        bvl[1] = *(const uint4v*)(wl + 8);
    };

    auto write_tile = [&]() {
        short hhi[16], hlo[16];
#pragma unroll
        for (int v = 0; v < 4; ++v)
#pragma unroll
            for (int e = 0; e < 4; ++e) {
                float f = av[v][e];
                unsigned short h = f2bf(f);
                hhi[v * 4 + e] = (short)h;
                hlo[v * 4 + e] = (short)f2bf(f - bf2f(h));
            }
        const int o = sr * 40 + sh * 16;
        *(short8*)(&As_hi[o])     = *(short8*)(&hhi[0]);
        *(short8*)(&As_hi[o + 8]) = *(short8*)(&hhi[8]);
        *(short8*)(&As_lo[o])     = *(short8*)(&hlo[0]);
        *(short8*)(&As_lo[o + 8]) = *(short8*)(&hlo[8]);
        *(short8*)(&Bs_hi[o])     = *(short8*)(&bvh[0]);
        *(short8*)(&Bs_hi[o + 8]) = *(short8*)(&bvh[1]);
        *(short8*)(&Bs_lo[o])     = *(short8*)(&bvl[0]);
        *(short8*)(&Bs_lo[o + 8]) = *(short8*)(&bvl[1]);
    };

    load_tile(0);
    for (int kt = 0; kt < KT; ++kt) {
        write_tile();
        __syncthreads();
        if (kt + 1 < KT) load_tile(kt + 1);   // global loads overlap MFMA below

        short8 ah[4], al[4], bh[4], bl[4];
#pragma unroll
        for (int i = 0; i < 4; ++i) {
            const int ra = (wr * 64 + i * 16 + lr) * 40 + lg * 8;
            ah[i] = *(const short8*)(&As_hi[ra]);
            al[i] = *(const short8*)(&As_lo[ra]);
            const int rb = (wc * 64 + i * 16 + lr) * 40 + lg * 8;
            bh[i] = *(const short8*)(&Bs_hi[rb]);
            bl[i] = *(const short8*)(&Bs_lo[rb]);
        }
#pragma unroll
        for (int i = 0; i < 4; ++i)
#pragma unroll
            for (int j = 0; j < 4; ++j) {
                acc[i][j] = __builtin_amdgcn_mfma_f32_16x16x32_bf16(ah[i], bh[j], acc[i][j], 0, 0, 0);
                acc[i][j] = __builtin_amdgcn_mfma_f32_16x16x32_bf16(al[i], bh[j], acc[i][j], 0, 0, 0);
                acc[i][j] = __builtin_amdgcn_mfma_f32_16x16x32_bf16(ah[i], bl[j], acc[i][j], 0, 0, 0);
            }
        __syncthreads();
    }

    // epilogue: C/D layout col=lane&15, row=(lane>>4)*4+reg [m89-verified]
#pragma unroll
    for (int i = 0; i < 4; ++i)
#pragma unroll
        for (int j = 0; j < 4; ++j) {
            const int col = n0 + wc * 64 + j * 16 + lr;
#pragma unroll
            for (int q = 0; q < 4; ++q) {
                const int row = m0 + wr * 64 + i * 16 + lg * 4 + q;
                float v = acc[i][j][q];
                if (EPI) v = fmaf(Dp[col], Up[(size_t)row * Nc + col], v);
                Cout[(size_t)row * Nc + col] = v;
            }
        }
}

// Phase A: per (b, chunk), local scan with zero init; save chunk-final state.
__global__ __launch_bounds__(128)
void scanA(const float* __restrict__ Bu, const float* __restrict__ wsc,
           float* __restrict__ finals) {
    int n = threadIdx.x;
    int blk = blockIdx.x;            // b*kChunks + c
    int b = blk >> 7, c = blk & 127;
    float Ar = wsc[n], Ai = wsc[128 + n];
    float xr = 0.f, xi = 0.f;
    size_t base = ((size_t)(b * kS + c * kClen)) * 256;
    for (int s = 0; s < kClen; ++s) {
        float br = Bu[base + n], bi = Bu[base + 128 + n];
        float tr = Ar * xr - Ai * xi + br;
        xi = Ar * xi + Ai * xr + bi;
        xr = tr;
        base += 256;
    }
    finals[(size_t)blk * 256 + n] = xr;
    finals[(size_t)blk * 256 + 128 + n] = xi;
}

// Phase B: serial scan over chunk finals -> exclusive carries.
__global__ __launch_bounds__(128)
void scanB(const float* __restrict__ finals, const float* __restrict__ ws,
           float* __restrict__ carries) {
    int n = threadIdx.x;
    int b = blockIdx.x;
    float Pr = ws[256 + n], Pi = ws[384 + n];
    float xr = 0.f, xi = 0.f;
    for (int c = 0; c < kChunks; ++c) {
        size_t o = ((size_t)(b * kChunks + c)) * 256;
        carries[o + n] = xr;
        carries[o + 128 + n] = xi;
        float fr = finals[o + n], fi = finals[o + 128 + n];
        float tr = Pr * xr - Pi * xi + fr;
        xi = Pr * xi + Pi * xr + fi;
        xr = tr;
    }
}

// Phase C: redo local scan seeded with carry; write x over Bu in place.
__global__ __launch_bounds__(128)
void scanC(float* __restrict__ Bu, const float* __restrict__ wsc,
           const float* __restrict__ carries) {
    int n = threadIdx.x;
    int blk = blockIdx.x;
    int b = blk >> 7, c = blk & 127;
    float Ar = wsc[n], Ai = wsc[128 + n];
    size_t co = (size_t)blk * 256;
    float xr = carries[co + n], xi = carries[co + 128 + n];
    size_t base = ((size_t)(b * kS + c * kClen)) * 256;
    for (int s = 0; s < kClen; ++s) {
        float br = Bu[base + n], bi = Bu[base + 128 + n];
        float tr = Ar * xr - Ai * xi + br;
        xi = Ar * xi + Ai * xr + bi;
        xr = tr;
        Bu[base + n] = xr;
        Bu[base + 128 + n] = xi;
        base += 256;
    }
}

extern "C" void kernel_launch(void* const* d_in, const int* in_sizes, int n_in,
                              void* d_out, int out_size, void* d_ws, size_t ws_size,
                              hipStream_t stream) {
    const float* u          = (const float*)d_in[0];
    const float* log_A_real = (const float*)d_in[1];
    const float* A_imag     = (const float*)d_in[2];
    const float* B_re       = (const float*)d_in[3];
    const float* B_im       = (const float*)d_in[4];
    const float* C_re       = (const float*)d_in[5];
    const float* C_im       = (const float*)d_in[6];
    const float* D          = (const float*)d_in[7];
    const float* log_dt     = (const float*)d_in[8];

    char* wsb = (char*)d_ws;
    float* wsf             = (float*)wsb;
    unsigned short* bw_hi  = (unsigned short*)(wsb + kOffBwHi);
    unsigned short* bw_lo  = (unsigned short*)(wsb + kOffBwLo);
    unsigned short* cw_hi  = (unsigned short*)(wsb + kOffCwHi);
    unsigned short* cw_lo  = (unsigned short*)(wsb + kOffCwLo);
    float* finals          = (float*)(wsb + kOffFinals);
    float* carries         = (float*)(wsb + kOffCarries);
    float* Bu              = (float*)(wsb + kOffBu);
    float* y               = (float*)d_out;

    pre1<<<1, 128, 0, stream>>>(log_A_real, A_imag, log_dt, wsf);
    pre2<<<(256 * kF) / 256, 256, 0, stream>>>(B_re, B_im, wsf, bw_hi, bw_lo);
    pre3<<<(kF * 256) / 256, 256, 0, stream>>>(C_re, C_im, cw_hi, cw_lo);

    // Bu[32768][256] = u[32768][768] @ Bw^T  (W stored [256][768])
    mfma_gemm<false><<<dim3(2, kM / 128), 256, 0, stream>>>(
        u, bw_hi, bw_lo, Bu, kM, 256, kF, nullptr, nullptr);

    scanA<<<kB * kChunks, 128, 0, stream>>>(Bu, wsf, finals);
    scanB<<<kB, 128, 0, stream>>>(finals, wsf, carries);
    scanC<<<kB * kChunks, 128, 0, stream>>>(Bu, wsf, carries);

    // y[32768][768] = x[32768][256] @ Cw^T + D*u  (W stored [768][256])
    mfma_gemm<true><<<dim3(kF / 128, kM / 128), 256, 0, stream>>>(
        Bu, cw_hi, cw_lo, y, kM, kF, 256, D, u);
}

// Round 3
// 110.113 us; speedup vs baseline: 3.2900x; 1.3304x over previous
//
#include <hip/hip_runtime.h>
#include <hip/hip_bf16.h>
#include <math.h>

typedef __attribute__((ext_vector_type(8))) short short8;
typedef __attribute__((ext_vector_type(4))) float f32x4;
typedef __attribute__((ext_vector_type(4))) unsigned int uint4v;

// Problem constants (B=8, S=4096, F=768, N=128)
constexpr int kF = 768;
constexpr int kN = 128;
constexpr int kB = 8;
constexpr int kS = 4096;
constexpr int kM = kB * kS;          // 32768 rows
constexpr int kChunks = 128;         // scan chunks along S
constexpr int kClen = 32;            // kChunks * kClen == kS

// Workspace layout (BYTE offsets), total ~36.4 MB (round-1 proved >=37.2 MB fits)
// [0, 3072)            scalars: A_bar(re,im), A_bar^32(re,im), coef(re,im) f32
// [3072, +393216)      Bw  [256][768] bf16 : row c = output col (c<128 Re, else Im)
// [396288, +393216)    Cw  [768][256] bf16 : row f, k<128 = C_re[f][k], else -C_im
// [789504, +1048576)   finals  [8*128][256] f32
// [1838080, +1048576)  carries [8*128][256] f32
// [2886656, +33554432) Bu / x  [32768][256] f32
constexpr size_t kOffBw      = 3072;
constexpr size_t kOffCw      = 396288;
constexpr size_t kOffFinals  = 789504;
constexpr size_t kOffCarries = 1838080;
constexpr size_t kOffBu      = 2886656;

__device__ __forceinline__ unsigned short f2bf(float f) {
    unsigned int u = __builtin_bit_cast(unsigned int, f);
    u += 0x7fffu + ((u >> 16) & 1u);   // round-to-nearest-even
    return (unsigned short)(u >> 16);
}
__device__ __forceinline__ float bf2f(unsigned short s) {
    unsigned int u = ((unsigned int)s) << 16;
    return __builtin_bit_cast(float, u);
}

__global__ __launch_bounds__(128)
void pre1(const float* __restrict__ log_A_real, const float* __restrict__ A_imag,
          const float* __restrict__ log_dt, float* __restrict__ ws) {
    int n = threadIdx.x;
    float dt = expf(log_dt[n]);
    float ar = -expf(log_A_real[n]);
    float ai = A_imag[n];
    float er = expf(ar * dt);
    float Ar = er * cosf(ai * dt);
    float Ai = er * sinf(ai * dt);
    // coef = (A_bar - 1) / (A_diag + 1e-8)
    float dr = ar + 1e-8f, di = ai;
    float inv = 1.0f / (dr * dr + di * di);
    float nr = Ar - 1.0f, ni = Ai;
    float cr = (nr * dr + ni * di) * inv;
    float ci = (ni * dr - nr * di) * inv;
    // A_bar^kClen by repeated multiply (matches scan semantics)
    float pr = 1.f, pi = 0.f;
    for (int i = 0; i < kClen; ++i) {
        float t = pr * Ar - pi * Ai;
        pi = pr * Ai + pi * Ar;
        pr = t;
    }
    ws[n] = Ar;        ws[128 + n] = Ai;
    ws[256 + n] = pr;  ws[384 + n] = pi;
    ws[512 + n] = cr;  ws[640 + n] = ci;
}

// Bw[c][f], c in [0,256): c<128 -> Re(coef_n * B[n][f]) (n=c), else Im (n=c-128)
__global__ __launch_bounds__(256)
void pre2(const float* __restrict__ B_re, const float* __restrict__ B_im,
          const float* __restrict__ wsf, unsigned short* __restrict__ bw) {
    int id = blockIdx.x * 256 + threadIdx.x;   // 0 .. 256*768-1
    int c = id / kF;
    int f = id - c * kF;
    int n = c & 127;
    float cr = wsf[512 + n], ci = wsf[640 + n];
    float br = B_re[n * kF + f], bi = B_im[n * kF + f];
    float v = (c < 128) ? (cr * br - ci * bi) : (cr * bi + ci * br);
    bw[id] = f2bf(v);
}

// Cw[f][k], k in [0,256): k<128 -> C_re[f][k], else -C_im[f][k-128]
__global__ __launch_bounds__(256)
void pre3(const float* __restrict__ C_re, const float* __restrict__ C_im,
          unsigned short* __restrict__ cw) {
    int id = blockIdx.x * 256 + threadIdx.x;   // 0 .. 768*256-1
    int f = id >> 8;
    int k = id & 255;
    float v = (k < 128) ? C_re[f * kN + k] : -C_im[f * kN + (k - 128)];
    cw[id] = f2bf(v);
}

// Single-bf16 MFMA GEMM: Cout[M][Nc] = A[M][K](f32 -> bf16 RNE) @ W[Nc][K](bf16)
// 128x128 tile, BK=32, 4 waves (2x2 of 64x64), 4x4 16x16x32 fragments, 1 MFMA each.
// Double-buffered LDS, ONE barrier per K-step; next-tile global loads issued
// before the barrier so latency hides under ds_read+MFMA.
template<bool EPI>
__global__ __launch_bounds__(256, 3)
void mfma_gemm(const float* __restrict__ A,
               const unsigned short* __restrict__ W,
               float* __restrict__ Cout, int M, int Nc, int K,
               const float* __restrict__ Dp, const float* __restrict__ Up) {
    // stride 40 shorts = 80 B: 16-lane frag reads land 2 lanes/bank (free, m136)
    __shared__ __align__(16) short As[2][128 * 40];
    __shared__ __align__(16) short Bs[2][128 * 40];

    // XCD-bijective swizzle (nwg % 8 == 0 for both grids: 512 and 1536)
    const int gx = gridDim.x;
    const int nwg = gx * gridDim.y;
    const int orig = blockIdx.y * gx + blockIdx.x;
    const int cpx = nwg >> 3;
    const int sw = (orig & 7) * cpx + (orig >> 3);
    const int m0 = (sw / gx) * 128;
    const int n0 = (sw % gx) * 128;

    const int t = threadIdx.x;
    const int sr = t >> 1;        // staging row (A) / col (W): 0..127
    const int sh = t & 1;         // which 16-wide half of the 32-k tile

    const int wave = t >> 6, lane = t & 63;
    const int wr = wave >> 1, wc = wave & 1;  // wave tile (64x64) coords
    const int lr = lane & 15, lg = lane >> 4;

    f32x4 acc[4][4] = {};
    const int KT = K >> 5;

    // staging registers (prefetched one K-tile ahead)
    f32x4 avf[4];
    uint4v wv0, wv1;

    auto load_tile = [&](int kt) {
        const int k0 = kt << 5;
        const float* ap = A + (size_t)(m0 + sr) * K + k0 + sh * 16;
        avf[0] = *(const f32x4*)(ap);
        avf[1] = *(const f32x4*)(ap + 4);
        avf[2] = *(const f32x4*)(ap + 8);
        avf[3] = *(const f32x4*)(ap + 12);
        const unsigned short* wp = W + (size_t)(n0 + sr) * K + k0 + sh * 16;
        wv0 = *(const uint4v*)(wp);
        wv1 = *(const uint4v*)(wp + 8);
    };

    auto write_tile = [&](int buf) {
        short h[16];
#pragma unroll
        for (int v = 0; v < 4; ++v)
#pragma unroll
            for (int e = 0; e < 4; ++e)
                h[v * 4 + e] = (short)f2bf(avf[v][e]);
        const int o = sr * 40 + sh * 16;
        *(short8*)(&As[buf][o])     = *(short8*)(&h[0]);
        *(short8*)(&As[buf][o + 8]) = *(short8*)(&h[8]);
        *(short8*)(&Bs[buf][o])     = *(short8*)(&wv0);
        *(short8*)(&Bs[buf][o + 8]) = *(short8*)(&wv1);
    };

    load_tile(0);
    for (int kt = 0; kt < KT; ++kt) {
        const int buf = kt & 1;
        write_tile(buf);
        if (kt + 1 < KT) load_tile(kt + 1);   // global loads span barrier + MFMA
        __syncthreads();                      // buf ready; prior reads of buf drained
        short8 ah[4], bh[4];
#pragma unroll
        for (int i = 0; i < 4; ++i) {
            ah[i] = *(const short8*)(&As[buf][(wr * 64 + i * 16 + lr) * 40 + lg * 8]);
            bh[i] = *(const short8*)(&Bs[buf][(wc * 64 + i * 16 + lr) * 40 + lg * 8]);
        }
#pragma unroll
        for (int i = 0; i < 4; ++i)
#pragma unroll
            for (int j = 0; j < 4; ++j)
                acc[i][j] = __builtin_amdgcn_mfma_f32_16x16x32_bf16(ah[i], bh[j], acc[i][j], 0, 0, 0);
        // no trailing barrier: next iteration writes the OTHER buffer; a write to
        // THIS buffer only happens after the next barrier, which drains these reads.
    }

    // epilogue: C/D layout col=lane&15, row=(lane>>4)*4+reg [m89-verified]
#pragma unroll
    for (int i = 0; i < 4; ++i)
#pragma unroll
        for (int j = 0; j < 4; ++j) {
            const int col = n0 + wc * 64 + j * 16 + lr;
#pragma unroll
            for (int q = 0; q < 4; ++q) {
                const int row = m0 + wr * 64 + i * 16 + lg * 4 + q;
                float v = acc[i][j][q];
                if (EPI) v = fmaf(Dp[col], Up[(size_t)row * Nc + col], v);
                Cout[(size_t)row * Nc + col] = v;
            }
        }
}

// Phase A: per (b, chunk), local scan with zero init; save chunk-final state.
__global__ __launch_bounds__(128)
void scanA(const float* __restrict__ Bu, const float* __restrict__ wsc,
           float* __restrict__ finals) {
    int n = threadIdx.x;
    int blk = blockIdx.x;            // b*kChunks + c
    int b = blk >> 7, c = blk & 127;
    float Ar = wsc[n], Ai = wsc[128 + n];
    float xr = 0.f, xi = 0.f;
    size_t base = ((size_t)(b * kS + c * kClen)) * 256;
    for (int s = 0; s < kClen; ++s) {
        float br = Bu[base + n], bi = Bu[base + 128 + n];
        float tr = Ar * xr - Ai * xi + br;
        xi = Ar * xi + Ai * xr + bi;
        xr = tr;
        base += 256;
    }
    finals[(size_t)blk * 256 + n] = xr;
    finals[(size_t)blk * 256 + 128 + n] = xi;
}

// Phase B: serial scan over chunk finals -> exclusive carries.
__global__ __launch_bounds__(128)
void scanB(const float* __restrict__ finals, const float* __restrict__ ws,
           float* __restrict__ carries) {
    int n = threadIdx.x;
    int b = blockIdx.x;
    float Pr = ws[256 + n], Pi = ws[384 + n];
    float xr = 0.f, xi = 0.f;
    for (int c = 0; c < kChunks; ++c) {
        size_t o = ((size_t)(b * kChunks + c)) * 256;
        carries[o + n] = xr;
        carries[o + 128 + n] = xi;
        float fr = finals[o + n], fi = finals[o + 128 + n];
        float tr = Pr * xr - Pi * xi + fr;
        xi = Pr * xi + Pi * xr + fi;
        xr = tr;
    }
}

// Phase C: redo local scan seeded with carry; write x over Bu in place.
__global__ __launch_bounds__(128)
void scanC(float* __restrict__ Bu, const float* __restrict__ wsc,
           const float* __restrict__ carries) {
    int n = threadIdx.x;
    int blk = blockIdx.x;
    int b = blk >> 7, c = blk & 127;
    float Ar = wsc[n], Ai = wsc[128 + n];
    size_t co = (size_t)blk * 256;
    float xr = carries[co + n], xi = carries[co + 128 + n];
    size_t base = ((size_t)(b * kS + c * kClen)) * 256;
    for (int s = 0; s < kClen; ++s) {
        float br = Bu[base + n], bi = Bu[base + 128 + n];
        float tr = Ar * xr - Ai * xi + br;
        xi = Ar * xi + Ai * xr + bi;
        xr = tr;
        Bu[base + n] = xr;
        Bu[base + 128 + n] = xi;
        base += 256;
    }
}

extern "C" void kernel_launch(void* const* d_in, const int* in_sizes, int n_in,
                              void* d_out, int out_size, void* d_ws, size_t ws_size,
                              hipStream_t stream) {
    const float* u          = (const float*)d_in[0];
    const float* log_A_real = (const float*)d_in[1];
    const float* A_imag     = (const float*)d_in[2];
    const float* B_re       = (const float*)d_in[3];
    const float* B_im       = (const float*)d_in[4];
    const float* C_re       = (const float*)d_in[5];
    const float* C_im       = (const float*)d_in[6];
    const float* D          = (const float*)d_in[7];
    const float* log_dt     = (const float*)d_in[8];

    char* wsb = (char*)d_ws;
    float* wsf            = (float*)wsb;
    unsigned short* bw    = (unsigned short*)(wsb + kOffBw);
    unsigned short* cw    = (unsigned short*)(wsb + kOffCw);
    float* finals         = (float*)(wsb + kOffFinals);
    float* carries        = (float*)(wsb + kOffCarries);
    float* Bu             = (float*)(wsb + kOffBu);
    float* y              = (float*)d_out;

    pre1<<<1, 128, 0, stream>>>(log_A_real, A_imag, log_dt, wsf);
    pre2<<<(256 * kF) / 256, 256, 0, stream>>>(B_re, B_im, wsf, bw);
    pre3<<<(kF * 256) / 256, 256, 0, stream>>>(C_re, C_im, cw);

    // Bu[32768][256] = u[32768][768] @ Bw^T  (W stored [256][768])
    mfma_gemm<false><<<dim3(2, kM / 128), 256, 0, stream>>>(
        u, bw, Bu, kM, 256, kF, nullptr, nullptr);

    scanA<<<kB * kChunks, 128, 0, stream>>>(Bu, wsf, finals);
    scanB<<<kB, 128, 0, stream>>>(finals, wsf, carries);
    scanC<<<kB * kChunks, 128, 0, stream>>>(Bu, wsf, carries);

    // y[32768][768] = x[32768][256] @ Cw^T + D*u  (W stored [768][256])
    mfma_gemm<true><<<dim3(kF / 128, kM / 128), 256, 0, stream>>>(
        Bu, cw, y, kM, kF, 256, D, u);
}